// Round 1
// 192.481 us; speedup vs baseline: 1.0366x; 1.0366x over previous
//
#include <hip/hip_runtime.h>
#include <hip/hip_bf16.h>
#include <stdint.h>

// Problem constants
#define Bsz 2
#define Hn  16
#define Ln  1024
#define Dn  64
#define Rn  16
#define En  4

typedef short short8 __attribute__((ext_vector_type(8)));
typedef float f32x4  __attribute__((ext_vector_type(4)));

__device__ __forceinline__ unsigned short f32_to_bf16_rne(float f) {
    union { float f; uint32_t u; } x; x.f = f;
    uint32_t u = x.u;
    u += 0x7FFFu + ((u >> 16) & 1u);   // round-to-nearest-even
    return (unsigned short)(u >> 16);
}

__device__ __forceinline__ float bf16_to_f32(unsigned short s) {
    union { uint32_t u; float f; } x; x.u = ((uint32_t)s) << 16;
    return x.f;
}

// async global->LDS, 16B per lane, wave-uniform base + lane*16 layout
__device__ __forceinline__ void gload_lds16(const void* g, void* l) {
    __builtin_amdgcn_global_load_lds(
        (const __attribute__((address_space(1))) unsigned int*)g,
        (__attribute__((address_space(3))) unsigned int*)l, 16, 0, 0);
}

// ---------------------------------------------------------------------------
// Kernel 1: u[b,h,l,r,e] = sum_d Q[b,h,l,d]*A1[r,h,d,e]   (z==0)
//           v[b,h,m,r,e] = sum_d K[b,h,m,d]*A2[r,h,e,d]   (z==1)
// ALSO exports bf16 copies of Q (linear, ws_q) and K (per-64-row-tile
// XOR-swizzled, ws_k) so score_kernel never touches f32 Q/K again and can
// stage K via global_load_lds with a bank-conflict-free read layout.
// ws layouts: ws_u/ws_v [bh][l][r*4+e] bf16; ws_q [bh][l][d] bf16;
// ws_k [bh][tile=l/64][ (row%64)*128 + d*2  XOR ((row%8)<<4) ] bytes.
// Grid: (L/16, B*H, 2), block 256.
// ---------------------------------------------------------------------------
__global__ __launch_bounds__(256) void uv_kernel(
    const float* __restrict__ Q, const float* __restrict__ K,
    const float* __restrict__ A1, const float* __restrict__ A2,
    unsigned short* __restrict__ ws_u, unsigned short* __restrict__ ws_v,
    unsigned short* __restrict__ ws_q, unsigned short* __restrict__ ws_k)
{
    __shared__ float Xs[16 * 68];          // 16 rows x 64 f32, pad->68
    __shared__ float Ah[16 * 65 * 4];      // [r][d] as float4, stride 65 f4 per r

    const int tid = threadIdx.x;
    const int bh  = blockIdx.y;
    const int h   = bh & 15;
    const int l0  = blockIdx.x * 16;
    const int isV = blockIdx.z;

    const float* X = (isV ? K : Q) + (size_t)bh * Ln * Dn;

    // stage 16 X rows (256 float4 total, 1 per thread)
    {
        const int row = tid >> 4, c4 = tid & 15;
        const float4 v = *(const float4*)&X[(size_t)(l0 + row) * Dn + c4 * 4];
        *(float4*)&Xs[row * 68 + c4 * 4] = v;
    }
    // stage A-slice for this head as Ah[r][d][e] (float4 over e)
    if (!isV) {
        #pragma unroll
        for (int i = 0; i < 4; ++i) {
            const int p = tid + i * 256;           // 0..1023
            const int r = p >> 6, d = p & 63;
            const float4 v = *(const float4*)&A1[(((size_t)r * Hn + h) * Dn + d) * En];
            *(float4*)&Ah[(r * 65 + d) * 4] = v;
        }
    } else {
        #pragma unroll
        for (int i = 0; i < 4; ++i) {
            const int p = tid + i * 256;
            const int r = p >> 6, d = p & 63;
            float4 v;
            v.x = A2[(((size_t)r * Hn + h) * En + 0) * Dn + d];
            v.y = A2[(((size_t)r * Hn + h) * En + 1) * Dn + d];
            v.z = A2[(((size_t)r * Hn + h) * En + 2) * Dn + d];
            v.w = A2[(((size_t)r * Hn + h) * En + 3) * Dn + d];
            *(float4*)&Ah[(r * 65 + d) * 4] = v;
        }
    }
    __syncthreads();

    // ---- export bf16 copy of this block's 16 X rows (128 x 16B chunks)
    if (tid < 128) {
        const int row = tid >> 3, ci = tid & 7;    // row 0..15, 8 f32 per chunk
        const float* src = &Xs[row * 68 + ci * 8];
        short8 o;
        #pragma unroll
        for (int j = 0; j < 8; ++j) o[j] = (short)f32_to_bf16_rne(src[j]);
        const int grow = l0 + row;
        if (!isV) {
            // Q: linear bf16 [bh][l][d]
            *(short8*)&ws_q[((size_t)bh * Ln + grow) * 64 + ci * 8] = o;
        } else {
            // K: pre-swizzled within each 64-row tile so that a LINEAR
            // global_load_lds copy lands in the XOR-swizzled LDS layout.
            const unsigned a  = (unsigned)(((grow & 63) * 128) + ci * 16);
            const unsigned sw = a ^ (((unsigned)(grow & 7)) << 4);
            *(short8*)((char*)ws_k + ((size_t)bh * Ln + (grow & ~63)) * 128 + sw) = o;
        }
    }

    // thread t: li = t>>4 (row), r = t&15; computes 4 outputs (e=0..3)
    const int li = tid >> 4, r = tid & 15;
    float ax = 0.f, ay = 0.f, az = 0.f, aw = 0.f;
    #pragma unroll
    for (int d = 0; d < Dn; ++d) {
        const float x = Xs[li * 68 + d];
        const float4 a = *(const float4*)&Ah[(r * 65 + d) * 4];
        ax += x * a.x; ay += x * a.y; az += x * a.z; aw += x * a.w;
    }
    unsigned short* dst = (isV ? ws_v : ws_u);
    ushort4 o;
    o.x = f32_to_bf16_rne(ax); o.y = f32_to_bf16_rne(ay);
    o.z = f32_to_bf16_rne(az); o.w = f32_to_bf16_rne(aw);
    *(ushort4*)&dst[((size_t)bh * Ln + l0 + li) * 64 + r * 4] = o;
}

// ---------------------------------------------------------------------------
// Kernel 2: out[bh,l,m] = (QK^T + u[l,rid]·v[m,rid]) * valid(rid)
// One block per 64x64 output tile, 4 waves. Wave w owns l-rows w*16..+15.
// All operands are pre-converted bf16:
//   - A-frags: 2 x 16B direct loads from ws_q (no LDS, no cvt)
//   - K tile:  global_load_lds (linear dest) of pre-swizzled ws_k; B-frag
//     ds_read_b128 applies the matching XOR -> bank-conflict-free
//   - u/v tiles: global_load_lds linear copies (8KB each)
// Zero staging VALU, zero ds_writes. LDS = 3*8192 = 24576 B -> 6 blocks/CU;
// __launch_bounds__(256,6) caps VGPR at 85 (est. ~70 live).
// Grid: (L/64, L/64, B*H), block 256.
// ---------------------------------------------------------------------------
__global__ __launch_bounds__(256, 6) void score_kernel(
    const int* __restrict__ rid,
    const unsigned short* __restrict__ ws_u, const unsigned short* __restrict__ ws_v,
    const unsigned short* __restrict__ ws_q, const unsigned short* __restrict__ ws_k,
    float* __restrict__ out)
{
    __shared__ unsigned short Ks[64 * 64];   // bf16, XOR-swizzled rows
    __shared__ unsigned short us[64 * 64];   // bf16, linear
    __shared__ unsigned short vs[64 * 64];   // bf16, linear

    const int tid = threadIdx.x;
    const int bh  = blockIdx.z;
    const int b   = bh >> 4;
    const int m0  = blockIdx.x * 64;
    const int l0  = blockIdx.y * 64;

    const int w    = tid >> 6;
    const int lane = tid & 63;
    const int quad = lane >> 4;
    const int ln   = lane & 15;

    // ---- kick off async LDS staging first (24 x 1KB wave-level DMAs total)
    {
        const char* kSrc = (const char*)ws_k + ((size_t)bh * Ln + m0) * 128;
        const char* uSrc = (const char*)ws_u + ((size_t)bh * Ln + l0) * 128;
        const char* vSrc = (const char*)ws_v + ((size_t)bh * Ln + m0) * 128;
        const int o0 = w * 2048 + lane * 16;
        const int o1 = o0 + 1024;
        gload_lds16(kSrc + o0, (char*)Ks + o0);
        gload_lds16(kSrc + o1, (char*)Ks + o1);
        gload_lds16(uSrc + o0, (char*)us + o0);
        gload_lds16(uSrc + o1, (char*)us + o1);
        gload_lds16(vSrc + o0, (char*)vs + o0);
        gload_lds16(vSrc + o1, (char*)vs + o1);
    }

    // ---- direct bf16 A-operand loads: lane's Q slice, 8 bf16 per k-step
    short8 aF[2];
    #pragma unroll
    for (int s = 0; s < 2; ++s)
        aF[s] = *(const short8*)&ws_q[((size_t)bh * Ln + l0 + w * 16 + ln) * 64 + s * 32 + quad * 8];

    // ---- prefetch the 16 rid values this thread needs
    int ridv[16];
    {
        const size_t ridRow0 = ((size_t)b * Ln + l0 + w * 16 + quad * 4) * Ln + m0 + ln;
        #pragma unroll
        for (int t = 0; t < 4; ++t)
            #pragma unroll
            for (int reg = 0; reg < 4; ++reg)
                ridv[t * 4 + reg] = rid[ridRow0 + (size_t)reg * Ln + t * 16];
    }

    __syncthreads();   // compiler drains vmcnt(0) here -> LDS tiles ready

    f32x4 acc[4];
    #pragma unroll
    for (int t = 0; t < 4; ++t) { f32x4 z = {0.f, 0.f, 0.f, 0.f}; acc[t] = z; }

    // B-frag: K row (t*16+ln), k = s*32 + quad*8 + j, swizzle-corrected read
    const int  xorv = (ln & 7) << 4;
    const char* KsB = (const char*)Ks;
    #pragma unroll
    for (int s = 0; s < 2; ++s) {
        const int co = (s * 64 + quad * 16) ^ xorv;
        #pragma unroll
        for (int t = 0; t < 4; ++t) {
            const short8 bF = *(const short8*)(KsB + t * 2048 + ln * 128 + co);
            acc[t] = __builtin_amdgcn_mfma_f32_16x16x32_bf16(aF[s], bF, acc[t], 0, 0, 0);
        }
    }

    // ---- epilogue: D layout row(l) = quad*4+reg (A side), col(m) = ln (B side)
    #pragma unroll
    for (int t = 0; t < 4; ++t) {
        const int m_local = t * 16 + ln;
        const int m = m0 + m_local;
        #pragma unroll
        for (int reg = 0; reg < 4; ++reg) {
            const int l_local = w * 16 + quad * 4 + reg;
            const int l = l0 + l_local;
            const int rv = ridv[t * 4 + reg];
            const bool valid = (rv >= 0) && (rv < Rn);
            const int r = valid ? rv : 0;
            const ushort4 uu = *(const ushort4*)&us[l_local * 64 + r * 4];
            const ushort4 vv = *(const ushort4*)&vs[m_local * 64 + r * 4];
            const float low = bf16_to_f32(uu.x) * bf16_to_f32(vv.x)
                            + bf16_to_f32(uu.y) * bf16_to_f32(vv.y)
                            + bf16_to_f32(uu.z) * bf16_to_f32(vv.z)
                            + bf16_to_f32(uu.w) * bf16_to_f32(vv.w);
            const float res = valid ? (acc[t][reg] + low) : 0.f;
            __builtin_nontemporal_store(res, &out[((size_t)bh * Ln + l) * Ln + m]);
        }
    }
}

extern "C" void kernel_launch(void* const* d_in, const int* in_sizes, int n_in,
                              void* d_out, int out_size, void* d_ws, size_t ws_size,
                              hipStream_t stream) {
    const float* Q   = (const float*)d_in[0];
    const float* K   = (const float*)d_in[1];
    const int*   rid = (const int*)d_in[2];
    const float* A1  = (const float*)d_in[3];
    const float* A2  = (const float*)d_in[4];
    float* out = (float*)d_out;

    const size_t seg = (size_t)Bsz * Hn * Ln * 64;                // 2M ushorts = 4 MB
    unsigned short* ws_u = (unsigned short*)d_ws;                 // 4 MB
    unsigned short* ws_v = ws_u + seg;                            // 4 MB
    unsigned short* ws_q = ws_v + seg;                            // 4 MB (bf16 Q, linear)
    unsigned short* ws_k = ws_q + seg;                            // 4 MB (bf16 K, swizzled)

    uv_kernel<<<dim3(Ln / 16, Bsz * Hn, 2), 256, 0, stream>>>(Q, K, A1, A2,
                                                              ws_u, ws_v, ws_q, ws_k);
    score_kernel<<<dim3(Ln / 64, Ln / 64, Bsz * Hn), 256, 0, stream>>>(rid, ws_u, ws_v,
                                                                       ws_q, ws_k, out);
}

// Round 2
// 189.705 us; speedup vs baseline: 1.0518x; 1.0146x over previous
//
#include <hip/hip_runtime.h>
#include <hip/hip_bf16.h>
#include <stdint.h>

// Problem constants
#define Bsz 2
#define Hn  16
#define Ln  1024
#define Dn  64
#define Rn  16
#define En  4

typedef short  short8 __attribute__((ext_vector_type(8)));
typedef float  f32x4  __attribute__((ext_vector_type(4)));
typedef _Float16 h2   __attribute__((ext_vector_type(2)));

__device__ __forceinline__ unsigned short f32_to_bf16_rne(float f) {
    union { float f; uint32_t u; } x; x.f = f;
    uint32_t u = x.u;
    u += 0x7FFFu + ((u >> 16) & 1u);   // round-to-nearest-even
    return (unsigned short)(u >> 16);
}

__device__ __forceinline__ unsigned short f32_to_f16_bits(float f) {
    union { _Float16 h; unsigned short s; } cv;
    cv.h = (_Float16)f;
    return cv.s;
}

// async global->LDS, 16B per lane, wave-uniform base + lane*16 layout
__device__ __forceinline__ void gload_lds16(const void* g, void* l) {
    __builtin_amdgcn_global_load_lds(
        (const __attribute__((address_space(1))) unsigned int*)g,
        (__attribute__((address_space(3))) unsigned int*)l, 16, 0, 0);
}

// ---------------------------------------------------------------------------
// Kernel 1: u[b,h,l,r,e] = sum_d Q[b,h,l,d]*A1[r,h,d,e]   (z==0)
//           v[b,h,m,r,e] = sum_d K[b,h,m,d]*A2[r,h,e,d]   (z==1)
// u/v stored as **f16** (more mantissa than bf16 at these magnitudes) so the
// score epilogue can use v_dot2_f32_f16.
// ALSO exports bf16 copies of Q (linear, ws_q) and K (per-64-row-tile
// XOR-swizzled, ws_k) so score_kernel never touches f32 Q/K again and can
// stage K via global_load_lds with a bank-conflict-free read layout.
// Grid: (L/16, B*H, 2), block 256.
// ---------------------------------------------------------------------------
__global__ __launch_bounds__(256) void uv_kernel(
    const float* __restrict__ Q, const float* __restrict__ K,
    const float* __restrict__ A1, const float* __restrict__ A2,
    unsigned short* __restrict__ ws_u, unsigned short* __restrict__ ws_v,
    unsigned short* __restrict__ ws_q, unsigned short* __restrict__ ws_k)
{
    __shared__ float Xs[16 * 68];          // 16 rows x 64 f32, pad->68
    __shared__ float Ah[16 * 65 * 4];      // [r][d] as float4, stride 65 f4 per r

    const int tid = threadIdx.x;
    const int bh  = blockIdx.y;
    const int h   = bh & 15;
    const int l0  = blockIdx.x * 16;
    const int isV = blockIdx.z;

    const float* X = (isV ? K : Q) + (size_t)bh * Ln * Dn;

    // stage 16 X rows (256 float4 total, 1 per thread)
    {
        const int row = tid >> 4, c4 = tid & 15;
        const float4 v = *(const float4*)&X[(size_t)(l0 + row) * Dn + c4 * 4];
        *(float4*)&Xs[row * 68 + c4 * 4] = v;
    }
    // stage A-slice for this head as Ah[r][d][e] (float4 over e)
    if (!isV) {
        #pragma unroll
        for (int i = 0; i < 4; ++i) {
            const int p = tid + i * 256;           // 0..1023
            const int r = p >> 6, d = p & 63;
            const float4 v = *(const float4*)&A1[(((size_t)r * Hn + h) * Dn + d) * En];
            *(float4*)&Ah[(r * 65 + d) * 4] = v;
        }
    } else {
        #pragma unroll
        for (int i = 0; i < 4; ++i) {
            const int p = tid + i * 256;
            const int r = p >> 6, d = p & 63;
            float4 v;
            v.x = A2[(((size_t)r * Hn + h) * En + 0) * Dn + d];
            v.y = A2[(((size_t)r * Hn + h) * En + 1) * Dn + d];
            v.z = A2[(((size_t)r * Hn + h) * En + 2) * Dn + d];
            v.w = A2[(((size_t)r * Hn + h) * En + 3) * Dn + d];
            *(float4*)&Ah[(r * 65 + d) * 4] = v;
        }
    }
    __syncthreads();

    // ---- export bf16 copy of this block's 16 X rows (128 x 16B chunks)
    if (tid < 128) {
        const int row = tid >> 3, ci = tid & 7;    // row 0..15, 8 f32 per chunk
        const float* src = &Xs[row * 68 + ci * 8];
        short8 o;
        #pragma unroll
        for (int j = 0; j < 8; ++j) o[j] = (short)f32_to_bf16_rne(src[j]);
        const int grow = l0 + row;
        if (!isV) {
            // Q: linear bf16 [bh][l][d]
            *(short8*)&ws_q[((size_t)bh * Ln + grow) * 64 + ci * 8] = o;
        } else {
            // K: pre-swizzled within each 64-row tile so that a LINEAR
            // global_load_lds copy lands in the XOR-swizzled LDS layout.
            const unsigned a  = (unsigned)(((grow & 63) * 128) + ci * 16);
            const unsigned sw = a ^ (((unsigned)(grow & 7)) << 4);
            *(short8*)((char*)ws_k + ((size_t)bh * Ln + (grow & ~63)) * 128 + sw) = o;
        }
    }

    // thread t: li = t>>4 (row), r = t&15; computes 4 outputs (e=0..3)
    const int li = tid >> 4, r = tid & 15;
    float ax = 0.f, ay = 0.f, az = 0.f, aw = 0.f;
    #pragma unroll
    for (int d = 0; d < Dn; ++d) {
        const float x = Xs[li * 68 + d];
        const float4 a = *(const float4*)&Ah[(r * 65 + d) * 4];
        ax += x * a.x; ay += x * a.y; az += x * a.z; aw += x * a.w;
    }
    unsigned short* dst = (isV ? ws_v : ws_u);
    ushort4 o;
    o.x = f32_to_f16_bits(ax); o.y = f32_to_f16_bits(ay);
    o.z = f32_to_f16_bits(az); o.w = f32_to_f16_bits(aw);
    *(ushort4*)&dst[((size_t)bh * Ln + l0 + li) * 64 + r * 4] = o;
}

// ---------------------------------------------------------------------------
// Kernel 2: out[bh,l,m] = (QK^T + u[l,rid]·v[m,rid]) * valid(rid)
// One block per 64x64 output tile, 4 waves. Wave w owns l-rows w*16..+15.
// All operands pre-converted:
//   - A-frags: 2 x 16B direct loads from ws_q (bf16, no LDS, no cvt)
//   - K tile:  global_load_lds (linear dest) of pre-swizzled ws_k; B-frag
//     ds_read_b128 applies the matching XOR -> bank-conflict-free
//   - u/v tiles (f16): global_load_lds linear copies (8KB each)
// Epilogue low-rank dot = 2 x v_dot2_f32_f16 per output (was ~15 VALU).
// LDS = 3*8192 = 24576 B -> 6 blocks/CU with __launch_bounds__(256,6).
// Grid: (L/64, L/64, B*H), block 256.
// ---------------------------------------------------------------------------
__global__ __launch_bounds__(256, 6) void score_kernel(
    const int* __restrict__ rid,
    const unsigned short* __restrict__ ws_u, const unsigned short* __restrict__ ws_v,
    const unsigned short* __restrict__ ws_q, const unsigned short* __restrict__ ws_k,
    float* __restrict__ out)
{
    __shared__ unsigned short Ks[64 * 64];   // bf16, XOR-swizzled rows
    __shared__ unsigned short us[64 * 64];   // f16, linear [l][r*4+e]
    __shared__ unsigned short vs[64 * 64];   // f16, linear [m][r*4+e]

    const int tid = threadIdx.x;
    const int bh  = blockIdx.z;
    const int b   = bh >> 4;
    const int m0  = blockIdx.x * 64;
    const int l0  = blockIdx.y * 64;

    const int w    = tid >> 6;
    const int lane = tid & 63;
    const int quad = lane >> 4;
    const int ln   = lane & 15;

    // ---- kick off async LDS staging first (24 x 1KB wave-level DMAs total)
    {
        const char* kSrc = (const char*)ws_k + ((size_t)bh * Ln + m0) * 128;
        const char* uSrc = (const char*)ws_u + ((size_t)bh * Ln + l0) * 128;
        const char* vSrc = (const char*)ws_v + ((size_t)bh * Ln + m0) * 128;
        const int o0 = w * 2048 + lane * 16;
        const int o1 = o0 + 1024;
        gload_lds16(kSrc + o0, (char*)Ks + o0);
        gload_lds16(kSrc + o1, (char*)Ks + o1);
        gload_lds16(uSrc + o0, (char*)us + o0);
        gload_lds16(uSrc + o1, (char*)us + o1);
        gload_lds16(vSrc + o0, (char*)vs + o0);
        gload_lds16(vSrc + o1, (char*)vs + o1);
    }

    // ---- direct bf16 A-operand loads: lane's Q slice, 8 bf16 per k-step
    short8 aF[2];
    #pragma unroll
    for (int s = 0; s < 2; ++s)
        aF[s] = *(const short8*)&ws_q[((size_t)bh * Ln + l0 + w * 16 + ln) * 64 + s * 32 + quad * 8];

    // ---- prefetch the 16 rid values this thread needs
    int ridv[16];
    {
        const size_t ridRow0 = ((size_t)b * Ln + l0 + w * 16 + quad * 4) * Ln + m0 + ln;
        #pragma unroll
        for (int t = 0; t < 4; ++t)
            #pragma unroll
            for (int reg = 0; reg < 4; ++reg)
                ridv[t * 4 + reg] = rid[ridRow0 + (size_t)reg * Ln + t * 16];
    }

    __syncthreads();   // compiler drains vmcnt(0) here -> LDS tiles ready

    f32x4 acc[4];
    #pragma unroll
    for (int t = 0; t < 4; ++t) { f32x4 z = {0.f, 0.f, 0.f, 0.f}; acc[t] = z; }

    // B-frag: K row (t*16+ln), k = s*32 + quad*8 + j, swizzle-corrected read
    const int  xorv = (ln & 7) << 4;
    const char* KsB = (const char*)Ks;
    #pragma unroll
    for (int s = 0; s < 2; ++s) {
        const int co = (s * 64 + quad * 16) ^ xorv;
        #pragma unroll
        for (int t = 0; t < 4; ++t) {
            const short8 bF = *(const short8*)(KsB + t * 2048 + ln * 128 + co);
            acc[t] = __builtin_amdgcn_mfma_f32_16x16x32_bf16(aF[s], bF, acc[t], 0, 0, 0);
        }
    }

    // ---- epilogue: D layout row(l) = quad*4+reg (A side), col(m) = ln (B side)
    #pragma unroll
    for (int t = 0; t < 4; ++t) {
        const int m_local = t * 16 + ln;
        const int m = m0 + m_local;
        #pragma unroll
        for (int reg = 0; reg < 4; ++reg) {
            const int l_local = w * 16 + quad * 4 + reg;
            const int l = l0 + l_local;
            const int rv = ridv[t * 4 + reg];
            const bool valid = ((unsigned)rv < (unsigned)Rn);
            const int r = rv & 15;                  // in-bounds addr; masked below
            const uint2 uraw = *(const uint2*)&us[l_local * 64 + r * 4];
            const uint2 vraw = *(const uint2*)&vs[m_local * 64 + r * 4];
            const h2 u01 = __builtin_bit_cast(h2, uraw.x);
            const h2 u23 = __builtin_bit_cast(h2, uraw.y);
            const h2 v01 = __builtin_bit_cast(h2, vraw.x);
            const h2 v23 = __builtin_bit_cast(h2, vraw.y);
            float low = __builtin_amdgcn_fdot2(u01, v01, 0.0f, false);
            low = __builtin_amdgcn_fdot2(u23, v23, low, false);
            const float res = valid ? (acc[t][reg] + low) : 0.f;
            __builtin_nontemporal_store(res, &out[((size_t)bh * Ln + l) * Ln + m]);
        }
    }
}

extern "C" void kernel_launch(void* const* d_in, const int* in_sizes, int n_in,
                              void* d_out, int out_size, void* d_ws, size_t ws_size,
                              hipStream_t stream) {
    const float* Q   = (const float*)d_in[0];
    const float* K   = (const float*)d_in[1];
    const int*   rid = (const int*)d_in[2];
    const float* A1  = (const float*)d_in[3];
    const float* A2  = (const float*)d_in[4];
    float* out = (float*)d_out;

    const size_t seg = (size_t)Bsz * Hn * Ln * 64;                // 2M ushorts = 4 MB
    unsigned short* ws_u = (unsigned short*)d_ws;                 // 4 MB (f16 u)
    unsigned short* ws_v = ws_u + seg;                            // 4 MB (f16 v)
    unsigned short* ws_q = ws_v + seg;                            // 4 MB (bf16 Q, linear)
    unsigned short* ws_k = ws_q + seg;                            // 4 MB (bf16 K, swizzled)

    uv_kernel<<<dim3(Ln / 16, Bsz * Hn, 2), 256, 0, stream>>>(Q, K, A1, A2,
                                                              ws_u, ws_v, ws_q, ws_k);
    score_kernel<<<dim3(Ln / 64, Ln / 64, Bsz * Hn), 256, 0, stream>>>(rid, ws_u, ws_v,
                                                                       ws_q, ws_k, out);
}